// Round 11
// baseline (285.714 us; speedup 1.0000x reference)
//
#include <hip/hip_runtime.h>
#include <math.h>

// FineGrainLoss: B=96, n1=196 (image tokens), n2=77 (text tokens), d=512.
#define BB 96
#define N1 196
#define N2 77
#define DD 512

#define IMGN (BB * N1 * DD)
#define TXTN (BB * N2 * DD)

// R20 CHAMPION RECOMBINATION — no new structure. Ten rounds established:
//   sim   : R6's kernel is the local optimum (196.5 us, MfmaUtil 35).
//           Refuted alternatives: fat-wave (R7 +11%), big-tile 1-block/CU
//           (R9 +15%), reg-staging (R5 spill), B-from-global (R10 +11%),
//           forced occupancy (R11-lesson: acc spills, 5.5x).
//           Load-bearing wins: 2 independent blocks/CU (R1, -29%) and
//           contiguous tiled staging (R6, -16%).
//   conv  : R16's strip-transpose, coalesced both sides.
//   ce    : R10's 16-wave shuffle-parallel version (overhead 90 -> 62 us).
// This file = R6 sim + R16 convert + R10 CE.
// Tiled h16 (R15): 1-KB tiles [16 rows x 32 k], cell = lq*16+lm, layout
// [bi][13 strips][16 kc] then [bt][5 cts][16 kc] -> contiguous 1-KB
// gload_lds reads (full 128-B lines on the L2->LDS path).
#define ATILES 13
#define NTILES 24              // 23 real + 1 dummy (3 stage-loads per wave)
#define BUFH (NTILES * 512)    // _Float16 per buffer (24,576 B)

#define TA_TILES (BB * 13 * 16)            // 19,968 A tiles
#define TB_TILES (BB * 5 * 16)             //  7,680 B tiles
#define NT_TILES (TA_TILES + TB_TILES)     // 27,648 tiles (28.3 MB)

#define NSTRIPS_A (BB * 13)    // 1,248
#define NSTRIPS_B (BB * 5)     //   480
#define NSTRIPS   (NSTRIPS_A + NSTRIPS_B)

typedef _Float16 f16x8 __attribute__((ext_vector_type(8)));  // 8 f16 (4 VGPR)
typedef float f4v __attribute__((ext_vector_type(4)));       // MFMA C/D

typedef unsigned int __attribute__((address_space(1))) as1_uint;
typedef unsigned int __attribute__((address_space(3))) as3_uint;

__device__ __forceinline__ void gload_lds16(const void* g, void* l) {
    __builtin_amdgcn_global_load_lds((const as1_uint*)g, (as3_uint*)l, 16, 0, 0);
}

// fp32 -> f16 convert + TILE pass, coalesced BOTH sides (R16's version).
// One 256-thread block per 16-row strip: read 16x512 fp32 contiguous,
// transpose via padded LDS, write the strip's 16 tiles (16 KB) contiguous.
__global__ __launch_bounds__(256) void convert_tiled_kernel(
    const float* __restrict__ img, const float* __restrict__ txt,
    _Float16* __restrict__ dst)
{
    __shared__ _Float16 sh[16 * 520];   // row pad 520 (1040 B = 65x16B)
    const int sid = blockIdx.x;
    const int tid = threadIdx.x;
    const float* base;
    int rowbase, rmax, tile0;
    if (sid < NSTRIPS_A) {
        const int bi = sid / 13, s = sid % 13;
        base = img + (size_t)bi * N1 * DD;
        rowbase = s * 16; rmax = N1 - 1;
        tile0 = sid * 16;
    } else {
        const int bs = sid - NSTRIPS_A;
        const int bt = bs / 5, ct = bs % 5;
        base = txt + (size_t)bt * N2 * DD;
        rowbase = ct * 16; rmax = N2 - 1;
        tile0 = TA_TILES + bs * 16;
    }
#pragma unroll
    for (int it = 0; it < 8; ++it) {
        const int u  = it * 256 + tid;   // 0..2047 float4-units
        const int r  = u >> 7;           // 0..15
        const int c4 = u & 127;          // float4 within row
        int q = rowbase + r; q = q > rmax ? rmax : q;
        float4 v = *(const float4*)(base + (size_t)q * DD + c4 * 4);
        union { _Float16 h[4]; uint2 u2; } o;
        o.h[0] = (_Float16)v.x; o.h[1] = (_Float16)v.y;
        o.h[2] = (_Float16)v.z; o.h[3] = (_Float16)v.w;
        *(uint2*)(sh + r * 520 + c4 * 4) = o.u2;
    }
    __syncthreads();
#pragma unroll
    for (int it = 0; it < 4; ++it) {
        const int w  = it * 256 + tid;   // 0..1023 16B-units
        const int kc = w >> 6;
        const int c  = w & 63;           // cell = lq*16+lm consumed by MFMA
        const int r16 = c & 15, k8 = c >> 4;
        uint4 val = *(const uint4*)(sh + r16 * 520 + kc * 32 + k8 * 8);
        *(uint4*)(dst + (size_t)(tile0 + kc) * 512 + c * 8) = val;
    }
}

// One K=32 sub-step: wave (g,h) computes strips [SG0, SG0+NS) x 5 cts of
// bt-half H. A strip s at tile s; B ct of half H at tile ATILES + H*5 + ct.
template <int SG0, int NS, int H>
__device__ __forceinline__ void compute_sub(const f16x8* __restrict__ fr,
                                            f4v* __restrict__ acc, int lane) {
    f16x8 b[5];
#pragma unroll
    for (int ct = 0; ct < 5; ++ct)
        b[ct] = fr[(ATILES + H * 5 + ct) * 64 + lane];
#pragma unroll
    for (int i = 0; i < NS; ++i) {
        f16x8 a = fr[(SG0 + i) * 64 + lane];
#pragma unroll
        for (int ct = 0; ct < 5; ++ct)
            acc[i * 5 + ct] = __builtin_amdgcn_mfma_f32_16x16x32_f16(
                a, b[ct], acc[i * 5 + ct], 0, 0, 0);
    }
}

// Reduction partials. C/D layout: col = lane&15, row = (lane>>4)*4 + reg.
// rp[H*208 + q]: per-bt-half rowmax (each (H, strip) owned by one wave).
// cp[g*160 + H*80 + col]: colmax partial per strip-group.
template <int SG0, int NS, int H>
__device__ __forceinline__ void reduce_phase1(const f4v* __restrict__ acc,
                                              int g, int lq, int lm,
                                              float* __restrict__ rp,
                                              float* __restrict__ cp) {
    float colm[5];
#pragma unroll
    for (int ct = 0; ct < 5; ++ct) colm[ct] = -INFINITY;
#pragma unroll
    for (int i = 0; i < NS; ++i) {
        const int s = SG0 + i;
        float rowm[4] = {-INFINITY, -INFINITY, -INFINITY, -INFINITY};
        bool rows_ok = (s != 12) || (lq == 0);   // rows >=196 are clamp-dups
#pragma unroll
        for (int ct = 0; ct < 5; ++ct) {
            f4v a = acc[i * 5 + ct];
            bool col_ok = (ct != 4) || (lm < N2 - 64);   // cols >=77 dups
            float cm = fmaxf(fmaxf(a[0], a[1]), fmaxf(a[2], a[3]));
            colm[ct] = fmaxf(colm[ct], rows_ok ? cm : -INFINITY);
#pragma unroll
            for (int r = 0; r < 4; ++r)
                rowm[r] = fmaxf(rowm[r], col_ok ? a[r] : -INFINITY);
        }
#pragma unroll
        for (int r = 0; r < 4; ++r) {
            float m = rowm[r];
            m = fmaxf(m, __shfl_xor(m, 1));
            m = fmaxf(m, __shfl_xor(m, 2));
            m = fmaxf(m, __shfl_xor(m, 4));
            m = fmaxf(m, __shfl_xor(m, 8));
            if (lm == 0) rp[H * 208 + s * 16 + lq * 4 + r] = m;
        }
    }
#pragma unroll
    for (int ct = 0; ct < 5; ++ct) {
        float m = colm[ct];
        m = fmaxf(m, __shfl_xor(m, 16));
        m = fmaxf(m, __shfl_xor(m, 32));
        if (lq == 0) cp[g * 160 + H * 80 + ct * 16 + lm] = m;
    }
}

// One block per (bi, btPair): S[208x160] = img[bi].(txt[bt0]|txt[bt1])^T.
// 512 threads = 8 waves in a 4x2 grid: strip-groups {4,3,3,3} x bt-half.
// __launch_bounds__(512,4): total-reg cap 128/wave -> no spill (acc[20]
// = 80 f32 + ~45 VGPR). Do NOT raise the min-waves arg (R11 lesson).
template <bool PRE>
__global__ __launch_bounds__(512, 4) void sim_mfma_kernel(
    const float* __restrict__ imgF, const float* __restrict__ txtF,
    const _Float16* __restrict__ h16,   // TILED (see convert_tiled_kernel)
    float* __restrict__ i2t, float* __restrict__ t2i)
{
    // ---- XCD-locality swizzle (4608 blocks = 8 xcd x 12 bi x 48 btPairs),
    // R6's proven layout (FETCH 47 MB, co-resident set < 4 MB L2) ----
    const int id  = blockIdx.x;
    const int xcd = id & 7;
    const int lid = id >> 3;           // 0..575
    const int w   = lid % 48;
    const int btq = lid / 48;          // 0..11
    const int btp = btq * 4 + (w & 3); // 0..47
    const int bi  = xcd * 12 + (w >> 2);
    const int bt0 = btp * 2;

    const int tid = threadIdx.x;
    const int wave = tid >> 6, lane = tid & 63;
    const int lm = lane & 15;
    const int lq = lane >> 4;
    const int g = wave >> 1;           // strip-group 0..3
    // const int h = wave & 1;         // bt-half (baked into templates)

    __shared__ __align__(16) _Float16 lds[3 * BUFH];   // 73,728 B
    // epilogue scratch aliases buffer 0: compute(15) reads buffer 15%3=0,
    // but barrier B at the end of iter 15 separates all its readers from
    // the reduction writes below.
    float* rp   = (float*)lds;           // 416: [half][208] rowmax
    float* cp   = (float*)lds + 416;     // 640: [g][160] colmax partials
    float* sws  = (float*)lds + 1056;    // 8
    float* scol = (float*)lds + 1064;    // 160

    // ---- staging descriptors ----
    // Thread stages cell `lane` of tile T = 8j + wave, j=0..2 (24 tiles,
    // exactly 3 per wave). PRE path: h16 is tiled — off = tileBase*512 +
    // lane*8; stage adds kc*512 (consecutive kc tiles are adjacent 1-KB
    // blocks -> each gload_lds reads a CONTIGUOUS 1 KB).
    int off[3];
    const float* fsrc[3];
#pragma unroll
    for (int j = 0; j < 3; ++j) {
        const int T = 8 * j + wave;
        if constexpr (PRE) {
            int t;
            if (T < ATILES) {
                t = (bi * 13 + T) * 16;
            } else if (T < 23) {
                const int ct = T - ATILES;      // 0..9
                const int bt = bt0 + (ct >= 5);
                t = TA_TILES + (bt * 5 + (ct % 5)) * 16;
            } else {
                t = 0;   // dummy tile: re-reads A tile 0, content never used
            }
            off[j] = t * 512 + lane * 8;
        } else {
            int o;
            bool isA = true;
            if (T < ATILES) {
                int q = T * 16 + lm; q = q > (N1 - 1) ? (N1 - 1) : q;
                o = (bi * N1 + q) * DD + lq * 8;
            } else if (T < 23) {
                isA = false;
                int ct = T - ATILES;
                int bt = bt0 + (ct >= 5);
                int r = (ct % 5) * 16 + lm; r = r > (N2 - 1) ? (N2 - 1) : r;
                o = (bt * N2 + r) * DD + lq * 8;
            } else {
                o = lq * 8;
            }
            off[j] = o;
            fsrc[j] = isA ? imgF : txtF;
        }
    }

    // async staging of K32 chunk kc into buffer b (3 gload_lds per wave,
    // each a contiguous 1-KB tile read)
    auto stage = [&](int kc, int b) {
        const int k0 = kc * 512;
#pragma unroll
        for (int j = 0; j < 3; ++j)
            gload_lds16(h16 + off[j] + k0,
                        lds + (b * NTILES + 8 * j + wave) * 512);
    };

    f4v acc[20];   // waves 0,1 (4-strip group): 20; others: 15 (tail dead)
#pragma unroll
    for (int i = 0; i < 20; ++i) acc[i] = (f4v){0.f, 0.f, 0.f, 0.f};

    auto do_compute = [&](const f16x8* fr) {
        if (wave == 0)      compute_sub<0, 4, 0>(fr, acc, lane);
        else if (wave == 1) compute_sub<0, 4, 1>(fr, acc, lane);
        else if (wave == 2) compute_sub<4, 3, 0>(fr, acc, lane);
        else if (wave == 3) compute_sub<4, 3, 1>(fr, acc, lane);
        else if (wave == 4) compute_sub<7, 3, 0>(fr, acc, lane);
        else if (wave == 5) compute_sub<7, 3, 1>(fr, acc, lane);
        else if (wave == 6) compute_sub<10, 3, 0>(fr, acc, lane);
        else                compute_sub<10, 3, 1>(fr, acc, lane);
    };

    if constexpr (PRE) {
        // ---- K loop: 16 steps of BK=32, 3 buffers, prefetch distance 2.
        // Counted vmcnt: each wave holds 3 loads/step, <=9 in flight;
        // vmcnt(6) waits only for the step about to be computed, so the
        // two younger steps' DMA stays in flight across both barriers.
        // Barrier A: all waves' loads for buf kc landed.
        // Barrier B: all waves done reading buf kc%3 before the DMA issued
        // next iteration (stage kc+3) overwrites it.
        stage(0, 0);
        stage(1, 1);
#pragma unroll 1
        for (int kc = 0; kc < 16; ++kc) {
            if (kc < 14) {
                stage(kc + 2, (kc + 2) % 3);
                asm volatile("s_waitcnt vmcnt(6)" ::: "memory");
            } else if (kc == 14) {
                asm volatile("s_waitcnt vmcnt(3)" ::: "memory");
            } else {
                asm volatile("s_waitcnt vmcnt(0)" ::: "memory");
            }
            __builtin_amdgcn_s_barrier();          // A
            asm volatile("" ::: "memory");
            do_compute((const f16x8*)(lds + (kc % 3) * BUFH));
            asm volatile("" ::: "memory");
            __builtin_amdgcn_s_barrier();          // B
        }
    } else {
        // correctness fallback (workspace too small): sync single-buffer
#pragma unroll 1
        for (int kc = 0; kc < 16; ++kc) {
            __syncthreads();
            const int k0 = kc * 32;
#pragma unroll
            for (int j = 0; j < 3; ++j) {
                const int T = 8 * j + wave;
                if (T < 23) {
                    float4 v0 = *(const float4*)(fsrc[j] + off[j] + k0);
                    float4 v1 = *(const float4*)(fsrc[j] + off[j] + k0 + 4);
                    union { f16x8 f; uint4 u; } o;
                    o.f[0] = (_Float16)v0.x; o.f[1] = (_Float16)v0.y;
                    o.f[2] = (_Float16)v0.z; o.f[3] = (_Float16)v0.w;
                    o.f[4] = (_Float16)v1.x; o.f[5] = (_Float16)v1.y;
                    o.f[6] = (_Float16)v1.z; o.f[7] = (_Float16)v1.w;
                    ((uint4*)lds)[T * 64 + lane] = o.u;
                }
            }
            __syncthreads();
            do_compute((const f16x8*)lds);
        }
        __syncthreads();
    }

    // ---- fused reductions (LDS buffer re-used as scratch) ----
    if (wave == 0)      reduce_phase1<0, 4, 0>(acc, g, lq, lm, rp, cp);
    else if (wave == 1) reduce_phase1<0, 4, 1>(acc, g, lq, lm, rp, cp);
    else if (wave == 2) reduce_phase1<4, 3, 0>(acc, g, lq, lm, rp, cp);
    else if (wave == 3) reduce_phase1<4, 3, 1>(acc, g, lq, lm, rp, cp);
    else if (wave == 4) reduce_phase1<7, 3, 0>(acc, g, lq, lm, rp, cp);
    else if (wave == 5) reduce_phase1<7, 3, 1>(acc, g, lq, lm, rp, cp);
    else if (wave == 6) reduce_phase1<10, 3, 0>(acc, g, lq, lm, rp, cp);
    else                reduce_phase1<10, 3, 1>(acc, g, lq, lm, rp, cp);
    __syncthreads();

    // i2t: mean over q<196 of rowmax, per bt-half.
    // Waves 0-3 (tid 0-255) cover half 0; waves 4-7 cover half 1.
    {
        const int half = tid >> 8;
        const int t = tid & 255;
        float v = (t < N1) ? rp[half * 208 + t] : 0.f;
        v += __shfl_xor(v, 1);  v += __shfl_xor(v, 2);  v += __shfl_xor(v, 4);
        v += __shfl_xor(v, 8);  v += __shfl_xor(v, 16); v += __shfl_xor(v, 32);
        if (lane == 0) sws[wave] = v;
    }
    // colmax merge across strip-groups
    if (tid < 160) {
        float m = fmaxf(fmaxf(cp[tid], cp[160 + tid]),
                        fmaxf(cp[320 + tid], cp[480 + tid]));
        scol[tid] = m;
    }
    __syncthreads();
    if (tid == 0)
        i2t[bi * BB + bt0] =
            (sws[0] + sws[1] + sws[2] + sws[3]) * (1.f / (float)N1);
    if (tid == 1)
        i2t[bi * BB + bt0 + 1] =
            (sws[4] + sws[5] + sws[6] + sws[7]) * (1.f / (float)N1);
    // t2i: mean over r<77 of colmax; wave0 -> bt0 (cols 0-79), wave1 -> bt1.
    if (wave < 2) {
        const float* c = scol + wave * 80;
        float cv = c[lane] + ((lane < N2 - 64) ? c[64 + lane] : 0.f);
        cv += __shfl_xor(cv, 1);  cv += __shfl_xor(cv, 2);  cv += __shfl_xor(cv, 4);
        cv += __shfl_xor(cv, 8);  cv += __shfl_xor(cv, 16); cv += __shfl_xor(cv, 32);
        if (lane == 0)
            t2i[(bt0 + wave) * BB + bi] = cv * (1.f / (float)N2);
    }
}

// CE with arange labels, parallelized (R10's version): 16 waves x 12 rows,
// wave-parallel max/sum via shuffles.
__global__ __launch_bounds__(1024) void ce_kernel(
    const float* __restrict__ i2t, const float* __restrict__ t2i,
    float* __restrict__ out)
{
    const int tid = threadIdx.x;
    const int wave = tid >> 6;
    const int lane = tid & 63;

    float total = 0.f;
#pragma unroll 1
    for (int rr = 0; rr < 12; ++rr) {
        const int row = rr * 16 + wave;        // 0..191
        const float* M = (row < BB) ? i2t : t2i;
        const int b = (row < BB) ? row : row - BB;
        const float* r = M + b * BB;
        float a = r[lane];
        float c = (lane < BB - 64) ? r[64 + lane] : -INFINITY;
        float m = fmaxf(a, c);
        m = fmaxf(m, __shfl_xor(m, 1));  m = fmaxf(m, __shfl_xor(m, 2));
        m = fmaxf(m, __shfl_xor(m, 4));  m = fmaxf(m, __shfl_xor(m, 8));
        m = fmaxf(m, __shfl_xor(m, 16)); m = fmaxf(m, __shfl_xor(m, 32));
        float s = expf(a - m) + ((lane < BB - 64) ? expf(c - m) : 0.f);
        s += __shfl_xor(s, 1);  s += __shfl_xor(s, 2);  s += __shfl_xor(s, 4);
        s += __shfl_xor(s, 8);  s += __shfl_xor(s, 16); s += __shfl_xor(s, 32);
        total += r[b] - (m + logf(s));
    }
    __shared__ float sp[16];
    if (lane == 0) sp[wave] = total;
    __syncthreads();
    if (tid == 0) {
        float t = 0.f;
#pragma unroll
        for (int i = 0; i < 16; ++i) t += sp[i];
        out[0] = -t * (1.f / (float)(2 * BB));
    }
}

extern "C" void kernel_launch(void* const* d_in, const int* in_sizes, int n_in,
                              void* d_out, int out_size, void* d_ws, size_t ws_size,
                              hipStream_t stream) {
    const float* img = (const float*)d_in[0];   // [96,196,512] fp32
    const float* txt = (const float*)d_in[1];   // [96,77,512] fp32
    float* i2t = (float*)d_ws;                  // [96,96]
    float* t2i = i2t + BB * BB;                 // [96,96]

    const size_t conv_off = 2 * BB * BB * sizeof(float);   // 16B-aligned
    const size_t need = conv_off + (size_t)NT_TILES * 512 * sizeof(_Float16);

    const int nblocks = BB * (BB / 2);   // 4608 = (bi, btPair)
    if (ws_size >= need) {
        _Float16* h16 = (_Float16*)((char*)d_ws + conv_off);
        convert_tiled_kernel<<<NSTRIPS, 256, 0, stream>>>(img, txt, h16);
        sim_mfma_kernel<true><<<nblocks, 512, 0, stream>>>(img, txt, h16, i2t, t2i);
    } else {
        sim_mfma_kernel<false><<<nblocks, 512, 0, stream>>>(img, txt, nullptr, i2t, t2i);
    }
    ce_kernel<<<1, 1024, 0, stream>>>(i2t, t2i, (float*)d_out);
}

// Round 13
// 274.650 us; speedup vs baseline: 1.0403x; 1.0403x over previous
//
#include <hip/hip_runtime.h>
#include <math.h>

// FineGrainLoss: B=96, n1=196 (image tokens), n2=77 (text tokens), d=512.
#define BB 96
#define N1 196
#define N2 77
#define DD 512

#define IMGN (BB * N1 * DD)
#define TXTN (BB * N2 * DD)

// R22 = R21 resubmitted verbatim (R12 bench was an infra failure — container
// acquisition failed twice; no measurement happened).
// R21 = R6 champion sim + two local tweaks:
//  (a) s_setprio(1) around the MFMA cluster (T5). Mechanism: 2 independent
//      blocks/CU at drifting phases — priority lets a compute-phase wave
//      preempt the other block's staging waves (the m191-positive regime;
//      null only in single-block lockstep, m190).
//  (b) dummy 24th tile removed: wave 7 stages 2 tiles/step (not 3) ->
//      -4.2% staging DMA + LDS-write port; per-wave counted vmcnt
//      (waves 0-6: 6/3/0, wave 7: 4/2/0). LDS 70,656 B, 2 blocks/CU.
// Everything else is the proven champion: 4608 blocks (bi, btPair),
// 512 thr / 8 waves 4x2 (strip-groups {4,3,3,3} x bt-half), BK=32,
// 3 buffers, prefetch dist 2, 2 barriers/step, tiled h16, R6 swizzle,
// R16 coalesced convert, R10 parallel CE.
// Established results: sim local optimum 196.5 us (MfmaUtil 35); refuted:
// fat-wave (+11%), big-tile 1-block/CU (+15%), reg-staging (spill),
// B-from-global (+11%), forced occupancy (spill 5.5x). Load-bearing:
// 2 independent blocks/CU (-29%), contiguous tiled staging (-16%).
// Overhead term (convert+CE+gaps) ~60-90 us with +-15-25 us run jitter.
#define ATILES 13
#define NTILES 23              // 13 A + 10 B, no dummy
#define BUFH (NTILES * 512)    // _Float16 per buffer (11,776 f16 = 23,552 B)

#define TA_TILES (BB * 13 * 16)            // 19,968 A tiles
#define TB_TILES (BB * 5 * 16)             //  7,680 B tiles
#define NT_TILES (TA_TILES + TB_TILES)     // 27,648 tiles (28.3 MB)

#define NSTRIPS_A (BB * 13)    // 1,248
#define NSTRIPS_B (BB * 5)     //   480
#define NSTRIPS   (NSTRIPS_A + NSTRIPS_B)

typedef _Float16 f16x8 __attribute__((ext_vector_type(8)));  // 8 f16 (4 VGPR)
typedef float f4v __attribute__((ext_vector_type(4)));       // MFMA C/D

typedef unsigned int __attribute__((address_space(1))) as1_uint;
typedef unsigned int __attribute__((address_space(3))) as3_uint;

__device__ __forceinline__ void gload_lds16(const void* g, void* l) {
    __builtin_amdgcn_global_load_lds((const as1_uint*)g, (as3_uint*)l, 16, 0, 0);
}

// fp32 -> f16 convert + TILE pass, coalesced BOTH sides (R16's version).
// One 256-thread block per 16-row strip: read 16x512 fp32 contiguous,
// transpose via padded LDS, write the strip's 16 tiles (16 KB) contiguous.
__global__ __launch_bounds__(256) void convert_tiled_kernel(
    const float* __restrict__ img, const float* __restrict__ txt,
    _Float16* __restrict__ dst)
{
    __shared__ _Float16 sh[16 * 520];   // row pad 520 (1040 B = 65x16B)
    const int sid = blockIdx.x;
    const int tid = threadIdx.x;
    const float* base;
    int rowbase, rmax, tile0;
    if (sid < NSTRIPS_A) {
        const int bi = sid / 13, s = sid % 13;
        base = img + (size_t)bi * N1 * DD;
        rowbase = s * 16; rmax = N1 - 1;
        tile0 = sid * 16;
    } else {
        const int bs = sid - NSTRIPS_A;
        const int bt = bs / 5, ct = bs % 5;
        base = txt + (size_t)bt * N2 * DD;
        rowbase = ct * 16; rmax = N2 - 1;
        tile0 = TA_TILES + bs * 16;
    }
#pragma unroll
    for (int it = 0; it < 8; ++it) {
        const int u  = it * 256 + tid;   // 0..2047 float4-units
        const int r  = u >> 7;           // 0..15
        const int c4 = u & 127;          // float4 within row
        int q = rowbase + r; q = q > rmax ? rmax : q;
        float4 v = *(const float4*)(base + (size_t)q * DD + c4 * 4);
        union { _Float16 h[4]; uint2 u2; } o;
        o.h[0] = (_Float16)v.x; o.h[1] = (_Float16)v.y;
        o.h[2] = (_Float16)v.z; o.h[3] = (_Float16)v.w;
        *(uint2*)(sh + r * 520 + c4 * 4) = o.u2;
    }
    __syncthreads();
#pragma unroll
    for (int it = 0; it < 4; ++it) {
        const int w  = it * 256 + tid;   // 0..1023 16B-units
        const int kc = w >> 6;
        const int c  = w & 63;           // cell = lq*16+lm consumed by MFMA
        const int r16 = c & 15, k8 = c >> 4;
        uint4 val = *(const uint4*)(sh + r16 * 520 + kc * 32 + k8 * 8);
        *(uint4*)(dst + (size_t)(tile0 + kc) * 512 + c * 8) = val;
    }
}

// One K=32 sub-step: wave (g,h) computes strips [SG0, SG0+NS) x 5 cts of
// bt-half H. A strip s at tile s; B ct of half H at tile ATILES + H*5 + ct.
template <int SG0, int NS, int H>
__device__ __forceinline__ void compute_sub(const f16x8* __restrict__ fr,
                                            f4v* __restrict__ acc, int lane) {
    f16x8 b[5];
#pragma unroll
    for (int ct = 0; ct < 5; ++ct)
        b[ct] = fr[(ATILES + H * 5 + ct) * 64 + lane];
#pragma unroll
    for (int i = 0; i < NS; ++i) {
        f16x8 a = fr[(SG0 + i) * 64 + lane];
#pragma unroll
        for (int ct = 0; ct < 5; ++ct)
            acc[i * 5 + ct] = __builtin_amdgcn_mfma_f32_16x16x32_f16(
                a, b[ct], acc[i * 5 + ct], 0, 0, 0);
    }
}

// Reduction partials. C/D layout: col = lane&15, row = (lane>>4)*4 + reg.
// rp[H*208 + q]: per-bt-half rowmax (each (H, strip) owned by one wave).
// cp[g*160 + H*80 + col]: colmax partial per strip-group.
template <int SG0, int NS, int H>
__device__ __forceinline__ void reduce_phase1(const f4v* __restrict__ acc,
                                              int g, int lq, int lm,
                                              float* __restrict__ rp,
                                              float* __restrict__ cp) {
    float colm[5];
#pragma unroll
    for (int ct = 0; ct < 5; ++ct) colm[ct] = -INFINITY;
#pragma unroll
    for (int i = 0; i < NS; ++i) {
        const int s = SG0 + i;
        float rowm[4] = {-INFINITY, -INFINITY, -INFINITY, -INFINITY};
        bool rows_ok = (s != 12) || (lq == 0);   // rows >=196 are clamp-dups
#pragma unroll
        for (int ct = 0; ct < 5; ++ct) {
            f4v a = acc[i * 5 + ct];
            bool col_ok = (ct != 4) || (lm < N2 - 64);   // cols >=77 dups
            float cm = fmaxf(fmaxf(a[0], a[1]), fmaxf(a[2], a[3]));
            colm[ct] = fmaxf(colm[ct], rows_ok ? cm : -INFINITY);
#pragma unroll
            for (int r = 0; r < 4; ++r)
                rowm[r] = fmaxf(rowm[r], col_ok ? a[r] : -INFINITY);
        }
#pragma unroll
        for (int r = 0; r < 4; ++r) {
            float m = rowm[r];
            m = fmaxf(m, __shfl_xor(m, 1));
            m = fmaxf(m, __shfl_xor(m, 2));
            m = fmaxf(m, __shfl_xor(m, 4));
            m = fmaxf(m, __shfl_xor(m, 8));
            if (lm == 0) rp[H * 208 + s * 16 + lq * 4 + r] = m;
        }
    }
#pragma unroll
    for (int ct = 0; ct < 5; ++ct) {
        float m = colm[ct];
        m = fmaxf(m, __shfl_xor(m, 16));
        m = fmaxf(m, __shfl_xor(m, 32));
        if (lq == 0) cp[g * 160 + H * 80 + ct * 16 + lm] = m;
    }
}

// One block per (bi, btPair): S[208x160] = img[bi].(txt[bt0]|txt[bt1])^T.
// 512 threads = 8 waves in a 4x2 grid: strip-groups {4,3,3,3} x bt-half.
// __launch_bounds__(512,4): total-reg cap 128/wave -> no spill (acc[20]
// = 80 f32 + ~45 VGPR). Do NOT raise the min-waves arg (R11 lesson).
template <bool PRE>
__global__ __launch_bounds__(512, 4) void sim_mfma_kernel(
    const float* __restrict__ imgF, const float* __restrict__ txtF,
    const _Float16* __restrict__ h16,   // TILED (see convert_tiled_kernel)
    float* __restrict__ i2t, float* __restrict__ t2i)
{
    // ---- XCD-locality swizzle (4608 blocks = 8 xcd x 12 bi x 48 btPairs),
    // R6's proven layout (FETCH 47 MB, co-resident set < 4 MB L2) ----
    const int id  = blockIdx.x;
    const int xcd = id & 7;
    const int lid = id >> 3;           // 0..575
    const int w   = lid % 48;
    const int btq = lid / 48;          // 0..11
    const int btp = btq * 4 + (w & 3); // 0..47
    const int bi  = xcd * 12 + (w >> 2);
    const int bt0 = btp * 2;

    const int tid = threadIdx.x;
    const int wave = tid >> 6, lane = tid & 63;
    const int lm = lane & 15;
    const int lq = lane >> 4;
    const int g = wave >> 1;           // strip-group 0..3
    // const int h = wave & 1;         // bt-half (baked into templates)

    __shared__ __align__(16) _Float16 lds[3 * BUFH];   // 70,656 B
    // epilogue scratch aliases buffer 0: compute(15) reads buffer 15%3=0,
    // but barrier B at the end of iter 15 separates all its readers from
    // the reduction writes below.
    float* rp   = (float*)lds;           // 416: [half][208] rowmax
    float* cp   = (float*)lds + 416;     // 640: [g][160] colmax partials
    float* sws  = (float*)lds + 1056;    // 8
    float* scol = (float*)lds + 1064;    // 160

    // ---- staging descriptors ----
    // Thread stages cell `lane` of tile T = 8j + wave, j=0..2; 23 real
    // tiles (waves 0-6 stage 3, wave 7 stages 2 — no dummy). PRE path:
    // h16 is tiled — off = tileBase*512 + lane*8; stage adds kc*512
    // (consecutive kc tiles adjacent -> each gload_lds reads a
    // CONTIGUOUS 1 KB).
    int off[3];
    const float* fsrc[3];
#pragma unroll
    for (int j = 0; j < 3; ++j) {
        const int T = 8 * j + wave;
        if constexpr (PRE) {
            int t = 0;
            if (T < ATILES) {
                t = (bi * 13 + T) * 16;
            } else if (T < 23) {
                const int ct = T - ATILES;      // 0..9
                const int bt = bt0 + (ct >= 5);
                t = TA_TILES + (bt * 5 + (ct % 5)) * 16;
            }
            off[j] = t * 512 + lane * 8;
        } else {
            int o = 0;
            bool isA = true;
            if (T < ATILES) {
                int q = T * 16 + lm; q = q > (N1 - 1) ? (N1 - 1) : q;
                o = (bi * N1 + q) * DD + lq * 8;
            } else if (T < 23) {
                isA = false;
                int ct = T - ATILES;
                int bt = bt0 + (ct >= 5);
                int r = (ct % 5) * 16 + lm; r = r > (N2 - 1) ? (N2 - 1) : r;
                o = (bt * N2 + r) * DD + lq * 8;
            }
            off[j] = o;
            fsrc[j] = isA ? imgF : txtF;
        }
    }

    // async staging of K32 chunk kc into buffer b (per-wave 3 or 2
    // contiguous 1-KB tile reads; guard is wave-uniform)
    auto stage = [&](int kc, int b) {
        const int k0 = kc * 512;
#pragma unroll
        for (int j = 0; j < 3; ++j)
            if (8 * j + wave < NTILES)
                gload_lds16(h16 + off[j] + k0,
                            lds + (b * NTILES + 8 * j + wave) * 512);
    };

    f4v acc[20];   // waves 0,1 (4-strip group): 20; others: 15 (tail dead)
#pragma unroll
    for (int i = 0; i < 20; ++i) acc[i] = (f4v){0.f, 0.f, 0.f, 0.f};

    auto do_compute = [&](const f16x8* fr) {
        if (wave == 0)      compute_sub<0, 4, 0>(fr, acc, lane);
        else if (wave == 1) compute_sub<0, 4, 1>(fr, acc, lane);
        else if (wave == 2) compute_sub<4, 3, 0>(fr, acc, lane);
        else if (wave == 3) compute_sub<4, 3, 1>(fr, acc, lane);
        else if (wave == 4) compute_sub<7, 3, 0>(fr, acc, lane);
        else if (wave == 5) compute_sub<7, 3, 1>(fr, acc, lane);
        else if (wave == 6) compute_sub<10, 3, 0>(fr, acc, lane);
        else                compute_sub<10, 3, 1>(fr, acc, lane);
    };

    if constexpr (PRE) {
        // ---- K loop: 16 steps of BK=32, 3 buffers, prefetch distance 2.
        // Counted vmcnt per wave class (waves 0-6 hold 3 loads/step,
        // wave 7 holds 2): steady-state wait for stage(kc) done =
        // vmcnt(2L) = 6 / 4; tail kc=14 -> vmcnt(L) = 3 / 2; kc=15 -> 0.
        // Barrier A: all waves' loads for buf kc landed.
        // Barrier B: all waves done reading buf kc%3 before the DMA issued
        // next iteration (stage kc+3) overwrites it.
        // setprio(1) brackets the MFMA cluster (T5): with 2 independent
        // blocks/CU at drifting phases, compute waves preempt the other
        // block's staging waves.
        stage(0, 0);
        stage(1, 1);
#pragma unroll 1
        for (int kc = 0; kc < 16; ++kc) {
            if (kc < 14) {
                stage(kc + 2, (kc + 2) % 3);
                if (wave < 7) asm volatile("s_waitcnt vmcnt(6)" ::: "memory");
                else          asm volatile("s_waitcnt vmcnt(4)" ::: "memory");
            } else if (kc == 14) {
                if (wave < 7) asm volatile("s_waitcnt vmcnt(3)" ::: "memory");
                else          asm volatile("s_waitcnt vmcnt(2)" ::: "memory");
            } else {
                asm volatile("s_waitcnt vmcnt(0)" ::: "memory");
            }
            __builtin_amdgcn_s_barrier();          // A
            asm volatile("" ::: "memory");
            __builtin_amdgcn_s_setprio(1);
            do_compute((const f16x8*)(lds + (kc % 3) * BUFH));
            __builtin_amdgcn_s_setprio(0);
            asm volatile("" ::: "memory");
            __builtin_amdgcn_s_barrier();          // B
        }
    } else {
        // correctness fallback (workspace too small): sync single-buffer
#pragma unroll 1
        for (int kc = 0; kc < 16; ++kc) {
            __syncthreads();
            const int k0 = kc * 32;
#pragma unroll
            for (int j = 0; j < 3; ++j) {
                const int T = 8 * j + wave;
                if (T < 23) {
                    float4 v0 = *(const float4*)(fsrc[j] + off[j] + k0);
                    float4 v1 = *(const float4*)(fsrc[j] + off[j] + k0 + 4);
                    union { f16x8 f; uint4 u; } o;
                    o.f[0] = (_Float16)v0.x; o.f[1] = (_Float16)v0.y;
                    o.f[2] = (_Float16)v0.z; o.f[3] = (_Float16)v0.w;
                    o.f[4] = (_Float16)v1.x; o.f[5] = (_Float16)v1.y;
                    o.f[6] = (_Float16)v1.z; o.f[7] = (_Float16)v1.w;
                    ((uint4*)lds)[T * 64 + lane] = o.u;
                }
            }
            __syncthreads();
            do_compute((const f16x8*)lds);
        }
        __syncthreads();
    }

    // ---- fused reductions (LDS buffer re-used as scratch) ----
    if (wave == 0)      reduce_phase1<0, 4, 0>(acc, g, lq, lm, rp, cp);
    else if (wave == 1) reduce_phase1<0, 4, 1>(acc, g, lq, lm, rp, cp);
    else if (wave == 2) reduce_phase1<4, 3, 0>(acc, g, lq, lm, rp, cp);
    else if (wave == 3) reduce_phase1<4, 3, 1>(acc, g, lq, lm, rp, cp);
    else if (wave == 4) reduce_phase1<7, 3, 0>(acc, g, lq, lm, rp, cp);
    else if (wave == 5) reduce_phase1<7, 3, 1>(acc, g, lq, lm, rp, cp);
    else if (wave == 6) reduce_phase1<10, 3, 0>(acc, g, lq, lm, rp, cp);
    else                reduce_phase1<10, 3, 1>(acc, g, lq, lm, rp, cp);
    __syncthreads();

    // i2t: mean over q<196 of rowmax, per bt-half.
    // Waves 0-3 (tid 0-255) cover half 0; waves 4-7 cover half 1.
    {
        const int half = tid >> 8;
        const int t = tid & 255;
        float v = (t < N1) ? rp[half * 208 + t] : 0.f;
        v += __shfl_xor(v, 1);  v += __shfl_xor(v, 2);  v += __shfl_xor(v, 4);
        v += __shfl_xor(v, 8);  v += __shfl_xor(v, 16); v += __shfl_xor(v, 32);
        if (lane == 0) sws[wave] = v;
    }
    // colmax merge across strip-groups
    if (tid < 160) {
        float m = fmaxf(fmaxf(cp[tid], cp[160 + tid]),
                        fmaxf(cp[320 + tid], cp[480 + tid]));
        scol[tid] = m;
    }
    __syncthreads();
    if (tid == 0)
        i2t[bi * BB + bt0] =
            (sws[0] + sws[1] + sws[2] + sws[3]) * (1.f / (float)N1);
    if (tid == 1)
        i2t[bi * BB + bt0 + 1] =
            (sws[4] + sws[5] + sws[6] + sws[7]) * (1.f / (float)N1);
    // t2i: mean over r<77 of colmax; wave0 -> bt0 (cols 0-79), wave1 -> bt1.
    if (wave < 2) {
        const float* c = scol + wave * 80;
        float cv = c[lane] + ((lane < N2 - 64) ? c[64 + lane] : 0.f);
        cv += __shfl_xor(cv, 1);  cv += __shfl_xor(cv, 2);  cv += __shfl_xor(cv, 4);
        cv += __shfl_xor(cv, 8);  cv += __shfl_xor(cv, 16); cv += __shfl_xor(cv, 32);
        if (lane == 0)
            t2i[(bt0 + wave) * BB + bi] = cv * (1.f / (float)N2);
    }
}

// CE with arange labels, parallelized (R10's version): 16 waves x 12 rows,
// wave-parallel max/sum via shuffles.
__global__ __launch_bounds__(1024) void ce_kernel(
    const float* __restrict__ i2t, const float* __restrict__ t2i,
    float* __restrict__ out)
{
    const int tid = threadIdx.x;
    const int wave = tid >> 6;
    const int lane = tid & 63;

    float total = 0.f;
#pragma unroll 1
    for (int rr = 0; rr < 12; ++rr) {
        const int row = rr * 16 + wave;        // 0..191
        const float* M = (row < BB) ? i2t : t2i;
        const int b = (row < BB) ? row : row - BB;
        const float* r = M + b * BB;
        float a = r[lane];
        float c = (lane < BB - 64) ? r[64 + lane] : -INFINITY;
        float m = fmaxf(a, c);
        m = fmaxf(m, __shfl_xor(m, 1));  m = fmaxf(m, __shfl_xor(m, 2));
        m = fmaxf(m, __shfl_xor(m, 4));  m = fmaxf(m, __shfl_xor(m, 8));
        m = fmaxf(m, __shfl_xor(m, 16)); m = fmaxf(m, __shfl_xor(m, 32));
        float s = expf(a - m) + ((lane < BB - 64) ? expf(c - m) : 0.f);
        s += __shfl_xor(s, 1);  s += __shfl_xor(s, 2);  s += __shfl_xor(s, 4);
        s += __shfl_xor(s, 8);  s += __shfl_xor(s, 16); s += __shfl_xor(s, 32);
        total += r[b] - (m + logf(s));
    }
    __shared__ float sp[16];
    if (lane == 0) sp[wave] = total;
    __syncthreads();
    if (tid == 0) {
        float t = 0.f;
#pragma unroll
        for (int i = 0; i < 16; ++i) t += sp[i];
        out[0] = -t * (1.f / (float)(2 * BB));
    }
}

extern "C" void kernel_launch(void* const* d_in, const int* in_sizes, int n_in,
                              void* d_out, int out_size, void* d_ws, size_t ws_size,
                              hipStream_t stream) {
    const float* img = (const float*)d_in[0];   // [96,196,512] fp32
    const float* txt = (const float*)d_in[1];   // [96,77,512] fp32
    float* i2t = (float*)d_ws;                  // [96,96]
    float* t2i = i2t + BB * BB;                 // [96,96]

    const size_t conv_off = 2 * BB * BB * sizeof(float);   // 16B-aligned
    const size_t need = conv_off + (size_t)NT_TILES * 512 * sizeof(_Float16);

    const int nblocks = BB * (BB / 2);   // 4608 = (bi, btPair)
    if (ws_size >= need) {
        _Float16* h16 = (_Float16*)((char*)d_ws + conv_off);
        convert_tiled_kernel<<<NSTRIPS, 256, 0, stream>>>(img, txt, h16);
        sim_mfma_kernel<true><<<nblocks, 512, 0, stream>>>(img, txt, h16, i2t, t2i);
    } else {
        sim_mfma_kernel<false><<<nblocks, 512, 0, stream>>>(img, txt, nullptr, i2t, t2i);
    }
    ce_kernel<<<1, 1024, 0, stream>>>(i2t, t2i, (float*)d_out);
}